// Round 1
// baseline (166.270 us; speedup 1.0000x reference)
//
#include <hip/hip_runtime.h>

#define L 2048
#define BS 4
#define CIN 32
#define COUT 32
#define HIDN 64
#define KK 8
#define TB 8
#define EPSV 1e-5f

__global__ void zero_sums(float* sums) {
    sums[threadIdx.x] = 0.f;
}

__global__ __launch_bounds__(256) void cc_main(
    const float* __restrict__ times,
    const float* __restrict__ features,
    const int*   __restrict__ mask,
    const float* __restrict__ W1,
    const float* __restrict__ b1,
    const float* __restrict__ W2,
    const float* __restrict__ b2,
    const float* __restrict__ Wsk,
    const float* __restrict__ bsk,
    float* __restrict__ out_pre,
    float* __restrict__ sums)   // sums[0..31]=sum, sums[32..63]=sumsq
{
    __shared__ float s_W1[CIN*HIDN];          // 8 KB
    __shared__ float s_te[TB][CIN];
    __shared__ float s_f [TB][CIN];
    __shared__ float s_F [TB][CIN];
    __shared__ float s_ft[TB][CIN];
    __shared__ float s_Q [TB][HIDN][CIN+1];   // pad 33 -> conflict-free writes
    __shared__ float s_r1[TB][COUT];
    __shared__ float s_r2[TB][COUT];

    const int tid = threadIdx.x;
    const int tl  = tid >> 5;        // local t (0..7)
    const int x   = tid & 31;        // lane within t-group = channel / output idx
    const int bt  = blockIdx.x * TB + tl;
    const int b   = bt >> 11;        // L = 2048
    const int t   = bt & (L - 1);

    for (int i = tid; i < CIN*HIDN; i += 256) s_W1[i] = W1[i];
    s_F[tl][x] = 0.f;

    float q0[CIN], q1[CIN];
    #pragma unroll
    for (int c = 0; c < CIN; c++) { q0[c] = 0.f; q1[c] = 0.f; }

    const float t_cur = times[b*L + t];
    const int   np_t  = mask[b*L + t];
    // _POS_VEC[x] = 10000^(2*(x//2)/32); store reciprocal
    const float inv_pos = 1.0f / powf(10000.0f, (2.0f * (float)(x >> 1)) / 32.0f);
    s_ft[tl][x] = features[(b*L + t)*CIN + x];
    __syncthreads();

    for (int k = 0; k < KK; k++) {
        const int idx   = t - (KK - 1) + k;       // pad = (K-1)*DIL = 7, ZERO_LAG
        const int valid = idx >= 0;
        const int idxc  = valid ? idx : 0;        // clip low only (idx <= t <= L-1)
        const int dmask = valid && np_t && mask[b*L + idxc];
        const float dt  = dmask ? (t_cur - times[b*L + idxc]) : 0.f;

        const float r = dt * inv_pos;
        s_te[tl][x] = ((x & 1) == 0) ? sinf(r) : cosf(r);
        // all masking folds into f: feat_g and kv share dt_mask, products vanish
        const float f = dmask ? features[(b*L + idxc)*CIN + x] : 0.f;
        s_f[tl][x] = f;
        s_F[tl][x] += f;
        __syncthreads();

        // h[j] = relu(b1[j] + te @ W1[:,j]); thread x owns j = x and x+32
        float ha = b1[x], hb = b1[x + 32];
        #pragma unroll
        for (int i = 0; i < CIN; i++) {
            const float tei = s_te[tl][i];
            ha = fmaf(tei, s_W1[i*HIDN + x],      ha);
            hb = fmaf(tei, s_W1[i*HIDN + x + 32], hb);
        }
        ha = fmaxf(ha, 0.f); hb = fmaxf(hb, 0.f);

        // Q[h,c] += h[h]*f[c]; thread x owns rows h=x and h=x+32 in registers
        #pragma unroll
        for (int c = 0; c < CIN; c++) {
            const float fc = s_f[tl][c];
            q0[c] = fmaf(ha, fc, q0[c]);
            q1[c] = fmaf(hb, fc, q1[c]);
        }
        __syncthreads();
    }

    #pragma unroll
    for (int c = 0; c < CIN; c++) {
        s_Q[tl][x][c]      = q0[c];
        s_Q[tl][x + 32][c] = q1[c];
    }
    __syncthreads();

    // out[o=x] = sum_{h,c} Q[h,c]*W2[h, c*32+o] + sum_c F[c]*b2[c*32+o]
    //          + features[t] @ W_skip[:,o] + b_skip[o]
    float acc = bsk[x];
    #pragma unroll
    for (int c = 0; c < CIN; c++) acc = fmaf(s_ft[tl][c], Wsk[c*COUT + x], acc);
    #pragma unroll
    for (int c = 0; c < CIN; c++) acc = fmaf(s_F[tl][c], b2[c*COUT + x], acc);
    #pragma unroll 2
    for (int h = 0; h < HIDN; h++) {
        const float* w2row = W2 + h*(CIN*COUT) + x;   // lanes x coalesced
        #pragma unroll
        for (int c = 0; c < CIN; c++) {
            acc = fmaf(s_Q[tl][h][c], w2row[c*COUT], acc);  // Q: LDS broadcast
        }
    }
    out_pre[(b*L + t)*COUT + x] = acc;

    // block-partial channel sums for the (b,t)-LayerNorm
    s_r1[tl][x] = acc;
    s_r2[tl][x] = acc * acc;
    __syncthreads();
    if (tid < 32) {
        float s1 = 0.f, s2 = 0.f;
        #pragma unroll
        for (int j = 0; j < TB; j++) { s1 += s_r1[j][x]; s2 += s_r2[j][x]; }
        atomicAdd(&sums[x],      s1);
        atomicAdd(&sums[32 + x], s2);
    }
}

__global__ __launch_bounds__(256) void cc_norm(
    float* __restrict__ out, const float* __restrict__ sums,
    const float* __restrict__ gamma, const float* __restrict__ beta)
{
    const int i = blockIdx.x * 256 + threadIdx.x;
    const int o = i & 31;
    const float n    = (float)(BS * L);
    const float mean = sums[o] / n;
    const float var  = sums[32 + o] / n - mean * mean;
    const float inv  = rsqrtf(var + EPSV);
    out[i] = gamma[o] * (out[i] - mean) * inv + beta[o];
}

extern "C" void kernel_launch(void* const* d_in, const int* in_sizes, int n_in,
                              void* d_out, int out_size, void* d_ws, size_t ws_size,
                              hipStream_t stream) {
    const float* times    = (const float*)d_in[0];
    const float* features = (const float*)d_in[1];
    const int*   mask     = (const int*)  d_in[2];
    const float* W1       = (const float*)d_in[3];
    const float* b1       = (const float*)d_in[4];
    const float* W2       = (const float*)d_in[5];
    const float* b2       = (const float*)d_in[6];
    const float* Wsk      = (const float*)d_in[7];
    const float* bsk      = (const float*)d_in[8];
    const float* gamma    = (const float*)d_in[9];
    const float* beta     = (const float*)d_in[10];
    float* out  = (float*)d_out;
    float* sums = (float*)d_ws;          // 64 floats of scratch

    zero_sums<<<1, 64, 0, stream>>>(sums);
    cc_main<<<(BS*L)/TB, 256, 0, stream>>>(times, features, mask, W1, b1,
                                           W2, b2, Wsk, bsk, out, sums);
    cc_norm<<<(BS*L*COUT)/256, 256, 0, stream>>>(out, sums, gamma, beta);
}

// Round 2
// 132.014 us; speedup vs baseline: 1.2595x; 1.2595x over previous
//
#include <hip/hip_runtime.h>

#define L 2048
#define BS 4
#define CIN 32
#define COUT 32
#define HIDN 64
#define KK 8
#define TB 8
#define EPSV 1e-5f

typedef _Float16 f16;
typedef _Float16 f16x8 __attribute__((ext_vector_type(8)));
typedef float f32x4 __attribute__((ext_vector_type(4)));

// Pack W2 into MFMA B-fragment order (f16) + zero the LN sums.
// B[k=hc][n=o] = W2_flat[hc*32 + o]  (since (hc>>5)*1024 + (hc&31)*32 = hc*32).
// Fragment f = kb*2+nt (kb: K-chunk of 32, nt: N-tile of 16); lane holds
// B[kb*32 + (lane>>4)*8 + j][nt*16 + (lane&15)], j=0..7 -> one b128 per frag.
__global__ __launch_bounds__(64) void w2_prep(const float* __restrict__ W2,
                                              f16* __restrict__ w2h,
                                              float* __restrict__ sums) {
    const int f    = blockIdx.x;        // 0..127
    const int lane = threadIdx.x;
    if (f == 0) sums[lane] = 0.f;       // 64 floats
    const int kb = f >> 1, nt = f & 1;
    const int m = lane & 15, qd = lane >> 4;
    #pragma unroll
    for (int j = 0; j < 8; j++) {
        float v = W2[(kb*32 + qd*8 + j)*32 + nt*16 + m];
        w2h[(f*64 + lane)*8 + j] = (f16)v;
    }
}

__global__ __launch_bounds__(256) void cc_main(
    const float* __restrict__ times,
    const float* __restrict__ features,
    const int*   __restrict__ mask,
    const float* __restrict__ W1,
    const float* __restrict__ b1,
    const float* __restrict__ b2,
    const float* __restrict__ Wsk,
    const float* __restrict__ bsk,
    const f16*   __restrict__ w2h,
    float* __restrict__ out_pre,
    float* __restrict__ sums)   // sums[0..31]=sum, sums[32..63]=sumsq
{
    __shared__ float s_W1[CIN*HIDN];            // 8 KB
    __shared__ f16   s_Q [TB][HIDN*CIN];        // 32 KB, row t-local, col hc=h*32+c
    __shared__ float s_te[TB][CIN];
    __shared__ float s_f [TB][CIN];
    __shared__ float s_ex[TB][CIN];
    __shared__ float s_part[4][TB][COUT];       // 4 KB, per-wave K-split partials

    const int tid = threadIdx.x;
    const int tl  = tid >> 5;        // local t (0..7)
    const int x   = tid & 31;
    const int bt  = blockIdx.x * TB + tl;
    const int b   = bt >> 11;        // L = 2048
    const int t   = bt & (L - 1);

    for (int i = tid; i < CIN*HIDN; i += 256) s_W1[i] = W1[i];

    float q0[CIN], q1[CIN];
    #pragma unroll
    for (int c = 0; c < CIN; c++) { q0[c] = 0.f; q1[c] = 0.f; }
    float Fx = 0.f;   // F[t][c=x] = sum_k f

    const float t_cur = times[b*L + t];
    const int   np_t  = mask[b*L + t];
    const float inv_pos = 1.0f / powf(10000.0f, (2.0f * (float)(x >> 1)) / 32.0f);

    // ---------------- Phase A: Q-build (verified in R1) ----------------
    for (int k = 0; k < KK; k++) {
        const int idx   = t - (KK - 1) + k;
        const int valid = idx >= 0;
        const int idxc  = valid ? idx : 0;
        const int dmask = valid && np_t && mask[b*L + idxc];
        const float dt  = dmask ? (t_cur - times[b*L + idxc]) : 0.f;

        const float r = dt * inv_pos;
        s_te[tl][x] = ((x & 1) == 0) ? sinf(r) : cosf(r);
        const float f = dmask ? features[(b*L + idxc)*CIN + x] : 0.f;
        s_f[tl][x] = f;
        Fx += f;
        __syncthreads();

        float ha = b1[x], hb = b1[x + 32];
        #pragma unroll
        for (int i = 0; i < CIN; i++) {
            const float tei = s_te[tl][i];
            ha = fmaf(tei, s_W1[i*HIDN + x],      ha);
            hb = fmaf(tei, s_W1[i*HIDN + x + 32], hb);
        }
        ha = fmaxf(ha, 0.f); hb = fmaxf(hb, 0.f);

        #pragma unroll
        for (int c = 0; c < CIN; c++) {
            const float fc = s_f[tl][c];
            q0[c] = fmaf(ha, fc, q0[c]);
            q1[c] = fmaf(hb, fc, q1[c]);
        }
        __syncthreads();
    }

    // Pack Q to f16 LDS. Row tl, q0 -> cols [x*32, x*32+32), q1 -> +1024.
    // Per-lane chunk rotation breaks the 16-way write conflict to 4-way.
    #pragma unroll
    for (int cj = 0; cj < 4; cj++) {
        const int cc = (x + cj) & 3;
        f16x8 v0, v1;
        #pragma unroll
        for (int e = 0; e < 8; e++) {
            v0[e] = (f16)q0[cc*8 + e];
            v1[e] = (f16)q1[cc*8 + e];
        }
        *(f16x8*)&s_Q[tl][x*32 + cc*8]        = v0;
        *(f16x8*)&s_Q[tl][1024 + x*32 + cc*8] = v1;
    }

    // extra[t][o] = b_skip[o] + feat[t]@Wsk[:,o] + F@b2-rows[:,o]
    s_te[tl][x] = Fx;
    s_f [tl][x] = features[(b*L + t)*CIN + x];
    __syncthreads();
    {
        float ex = bsk[x];
        #pragma unroll
        for (int c = 0; c < CIN; c++) ex = fmaf(s_f [tl][c], Wsk[c*COUT + x], ex);
        #pragma unroll
        for (int c = 0; c < CIN; c++) ex = fmaf(s_te[tl][c], b2 [c*COUT + x], ex);
        s_ex[tl][x] = ex;
    }
    __syncthreads();   // also covers s_Q writes before MFMA reads

    // ---------------- Phase B: MFMA epilogue ----------------
    // out[t][o] = sum_hc Q[t][hc] * W2h-B[hc][o]; M-tile 16 (rows 8..15 dup of
    // 0..7 via broadcast), K=2048 split over 4 waves, N = 2 tiles of 16.
    {
        const int wv   = tid >> 6;
        const int lane = tid & 63;
        const int m    = lane & 15, qd = lane >> 4;
        f32x4 C0 = {0.f, 0.f, 0.f, 0.f};
        f32x4 C1 = {0.f, 0.f, 0.f, 0.f};
        #pragma unroll 4
        for (int kb = wv*16; kb < wv*16 + 16; kb++) {
            const f16x8 a  = *(const f16x8*)&s_Q[m & 7][kb*32 + qd*8];
            const f16x8 b0 = *(const f16x8*)&w2h[((kb*2 + 0)*64 + lane)*8];
            const f16x8 b1 = *(const f16x8*)&w2h[((kb*2 + 1)*64 + lane)*8];
            C0 = __builtin_amdgcn_mfma_f32_16x16x32_f16(a, b0, C0, 0, 0, 0);
            C1 = __builtin_amdgcn_mfma_f32_16x16x32_f16(a, b1, C1, 0, 0, 0);
        }
        // D layout: col = lane&15, row = qd*4 + r; rows 0..7 are the real t's
        if (qd < 2) {
            #pragma unroll
            for (int r = 0; r < 4; r++) {
                const int row = qd*4 + r;
                s_part[wv][row][m]      = C0[r];
                s_part[wv][row][16 + m] = C1[r];
            }
        }
    }
    __syncthreads();

    // Reduce K-split partials, add extras, write out + LN partial sums
    float val = s_ex[tl][x];
    #pragma unroll
    for (int w = 0; w < 4; w++) val += s_part[w][tl][x];
    out_pre[(b*L + t)*COUT + x] = val;
    s_te[tl][x] = val;
    s_f [tl][x] = val * val;
    __syncthreads();
    if (tid < 32) {
        float s1 = 0.f, s2 = 0.f;
        #pragma unroll
        for (int j = 0; j < TB; j++) { s1 += s_te[j][x]; s2 += s_f[j][x]; }
        atomicAdd(&sums[x],      s1);
        atomicAdd(&sums[32 + x], s2);
    }
}

__global__ __launch_bounds__(256) void cc_norm(
    float* __restrict__ out, const float* __restrict__ sums,
    const float* __restrict__ gamma, const float* __restrict__ beta)
{
    const int i = blockIdx.x * 256 + threadIdx.x;
    const int o = i & 31;
    const float n    = (float)(BS * L);
    const float mean = sums[o] / n;
    const float var  = sums[32 + o] / n - mean * mean;
    const float inv  = rsqrtf(var + EPSV);
    out[i] = gamma[o] * (out[i] - mean) * inv + beta[o];
}

extern "C" void kernel_launch(void* const* d_in, const int* in_sizes, int n_in,
                              void* d_out, int out_size, void* d_ws, size_t ws_size,
                              hipStream_t stream) {
    const float* times    = (const float*)d_in[0];
    const float* features = (const float*)d_in[1];
    const int*   mask     = (const int*)  d_in[2];
    const float* W1       = (const float*)d_in[3];
    const float* b1       = (const float*)d_in[4];
    const float* W2       = (const float*)d_in[5];
    const float* b2       = (const float*)d_in[6];
    const float* Wsk      = (const float*)d_in[7];
    const float* bsk      = (const float*)d_in[8];
    const float* gamma    = (const float*)d_in[9];
    const float* beta     = (const float*)d_in[10];
    float* out  = (float*)d_out;
    float* sums = (float*)d_ws;                       // 64 floats
    f16*   w2h  = (f16*)((char*)d_ws + 256);          // 128 KB, 16B-aligned

    w2_prep<<<128, 64, 0, stream>>>(W2, w2h, sums);
    cc_main<<<(BS*L)/TB, 256, 0, stream>>>(times, features, mask, W1, b1,
                                           b2, Wsk, bsk, w2h, out, sums);
    cc_norm<<<(BS*L*COUT)/256, 256, 0, stream>>>(out, sums, gamma, beta);
}